// Round 9
// baseline (395.851 us; speedup 1.0000x reference)
//
#include <hip/hip_runtime.h>
#include <math.h>

#define B_   128
#define R_   1152
#define RS_  64
#define RCH_ 18            // R_/RS_
#define NBINS 72           // 1152/16 colsum bins
#define NBLK_G 1024        // 16 bt x 64 rs

// ws float offsets
#define WS_S    0          // 32768 (atomic-accumulated s[b][co])
#define WS_V    32768      // 32768
#define WS_BLOG 65536      // 18432
#define WS_CTRL 84480      // 2368: ctr0/1/2 @ 0/16/32, cs0 @+64 (72*16), cs1 @+1216
#define WS_XT   86912      // 1179648 (xT4[r*256 + b*2 + h])
#define WS_WT   1266560    // 2359296 (Wt4[r*512 + d*64 + co4])

__device__ __forceinline__ float squashf(float s) {
    return s * fabsf(s) / (1.0f + s * s);
}

// ---------- T: Wt transpose + xT transpose + zero s/ctrl (replay-safe reset)
__global__ __launch_bounds__(512) void wtrans_k(const float* __restrict__ W,
                                                const float* __restrict__ x,
                                                float* __restrict__ wt,
                                                float* __restrict__ xt,
                                                float* __restrict__ s,
                                                float* __restrict__ ctrl) {
    const int r = blockIdx.x;
    const int t = threadIdx.x;
    __shared__ float4 sh[520];
    const float4* __restrict__ W4 = (const float4*)W;
    const float4* __restrict__ X4 = (const float4*)x;
    float4* __restrict__ Wt4 = (float4*)wt;
    float4* __restrict__ XT4 = (float4*)xt;

    // side duties: zero s (blocks 0..63) and ctrl (block 0) each graph replay
    if (r < 64) s[r * 512 + t] = 0.0f;
    if (r == 0) {
        for (int u = t; u < 2368; u += 512) ctrl[u] = 0.0f;
    }
    // x column gather done ONCE here (was per-a_k-block): xT4[r*256 + b*2 + h]
    if (t < 256) {
        XT4[r * 256 + t] = X4[((t >> 1) * R_ + r) * 2 + (t & 1)];
    }

    sh[(t & 7) * 65 + (t >> 3)] = W4[r * 512 + t];     // t = co4*8 + d
    __syncthreads();
    Wt4[r * 512 + t] = sh[(t >> 6) * 65 + (t & 63)];   // t = d*64 + co4
}

// ---------- G+S: s[b,co] += sum_{r in chunk,i} x[b,r,i]*cw[r,c]*W[r,co,i]
// grid dim3(16 bt, 64 rs) x 256 — R8's proven body; sp store replaced by
// atomicAdd into s (64 adds/addr, lane-distinct). Last-arriving block
// (release-counter, no spin) squashes s -> dst and re-zeroes s.
// IT==0: cw = 1/R. IT>=1: cw = exp(blog)/colsum from 72x16 bins.
template <int IT>
__global__ __launch_bounds__(256) void gemm_s_k(const float* __restrict__ x,
                                                const float* __restrict__ wt,
                                                const float* __restrict__ blog,
                                                const float* __restrict__ colbins,
                                                float* __restrict__ s,
                                                float* __restrict__ dst,
                                                unsigned int* __restrict__ ctr) {
    const int bt  = blockIdx.x;           // 0..15 (8 b each)
    const int rs  = blockIdx.y;
    const int t   = threadIdx.x;
    const int co4 = t & 63;
    const int b4  = t >> 6;               // 0..3 (2 b each)
    const int c   = co4 >> 2;
    const int r0  = rs * RCH_;

    __shared__ float4 xl4[288];           // 8 b x 18 r x 2 f4 = 4.6 KB
    __shared__ float  cwl[RCH_ * 16];
    __shared__ float  colinv_sh[16];
    __shared__ float  psum[256];
    __shared__ unsigned int old_sh;

    const float4* __restrict__ X4  = (const float4*)x;
    const float4* __restrict__ Wt4 = (const float4*)wt;

    // stage x tile: 8 b x 18 r x 2 f4
    #pragma unroll
    for (int k = 0; k < 2; ++k) {
        const int u = t + k * 256;
        if (u < 288) {
            const int bl = u / 36, rem = u % 36;
            xl4[u] = X4[((bt * 8 + bl) * R_ + r0) * 2 + rem];
        }
    }

    // prepass: colinv from bins (16 j-lanes x 16 cc), then cwl rows
    if (IT != 0) {
        const int cc = t & 15, jb = t >> 4;
        float sm = 0.f;
        for (int j = jb; j < NBINS; j += 16) sm += colbins[j * 16 + cc];
        psum[t] = sm;
        __syncthreads();
        if (t < 16) {
            float tot = 0.f;
            #pragma unroll
            for (int k2 = 0; k2 < 16; ++k2) tot += psum[k2 * 16 + t];
            colinv_sh[t] = 1.0f / tot;
        }
        __syncthreads();
        for (int u2 = t; u2 < RCH_ * 16; u2 += 256) {
            const int rl = u2 >> 4, c2 = u2 & 15;
            cwl[u2] = __expf(blog[(r0 + rl) * 16 + c2]) * colinv_sh[c2];
        }
    }
    __syncthreads();

    float acc[2][4];
    #pragma unroll
    for (int j = 0; j < 2; ++j)
        #pragma unroll
        for (int q = 0; q < 4; ++q) acc[j][q] = 0.f;

    // R8-identical hot loop (named w0..w7, unroll 3, j-extent 2)
    #pragma unroll 3
    for (int rr = 0; rr < RCH_; ++rr) {
        const float cwv = (IT == 0) ? (1.0f / (float)R_) : cwl[rr * 16 + c];
        const float4* wp = Wt4 + ((size_t)(r0 + rr) << 9) + co4;   // lane-stride 16B
        const float4 w0 = wp[  0], w1 = wp[ 64], w2 = wp[128], w3 = wp[192];
        const float4 w4 = wp[256], w5 = wp[320], w6 = wp[384], w7 = wp[448];
        #pragma unroll
        for (int j = 0; j < 2; ++j) {
            const float4 xa = xl4[(b4 * 2 + j) * 36 + rr * 2];
            const float4 xb = xl4[(b4 * 2 + j) * 36 + rr * 2 + 1];
            const float d0 = w0.x*xa.x + w0.y*xa.y + w0.z*xa.z + w0.w*xa.w
                           + w1.x*xb.x + w1.y*xb.y + w1.z*xb.z + w1.w*xb.w;
            const float d1 = w2.x*xa.x + w2.y*xa.y + w2.z*xa.z + w2.w*xa.w
                           + w3.x*xb.x + w3.y*xb.y + w3.z*xb.z + w3.w*xb.w;
            const float d2 = w4.x*xa.x + w4.y*xa.y + w4.z*xa.z + w4.w*xa.w
                           + w5.x*xb.x + w5.y*xb.y + w5.z*xb.z + w5.w*xb.w;
            const float d3 = w6.x*xa.x + w6.y*xa.y + w6.z*xa.z + w6.w*xa.w
                           + w7.x*xb.x + w7.y*xb.y + w7.z*xb.z + w7.w*xb.w;
            acc[j][0] = fmaf(cwv, d0, acc[j][0]);
            acc[j][1] = fmaf(cwv, d1, acc[j][1]);
            acc[j][2] = fmaf(cwv, d2, acc[j][2]);
            acc[j][3] = fmaf(cwv, d3, acc[j][3]);
        }
    }

    // accumulate into s: lane-distinct addresses, 64 adds/address total
    #pragma unroll
    for (int j = 0; j < 2; ++j) {
        const int b = bt * 8 + b4 * 2 + j;
        float* sb = s + b * 256 + co4 * 4;
        atomicAdd(&sb[0], acc[j][0]);
        atomicAdd(&sb[1], acc[j][1]);
        atomicAdd(&sb[2], acc[j][2]);
        atomicAdd(&sb[3], acc[j][3]);
    }

    // last-arrival squash tail (no spin; release pattern)
    __syncthreads();                      // drains this block's atomics (vmcnt 0)
    if (t == 0) {
        __threadfence();                  // order atomics before counter
        old_sh = atomicAdd(ctr, 1u);
    }
    __syncthreads();
    if (old_sh != (unsigned int)(NBLK_G - 1)) return;

    // this block arrived last: every other block's s-adds happened-before
    // its ctr increment. Agent-scope loads bypass stale local caches.
    #pragma unroll 8
    for (int k = 0; k < 128; ++k) {
        const int u = t + k * 256;        // 32768 floats
        const float sv = __hip_atomic_load(&s[u], __ATOMIC_RELAXED,
                                           __HIP_MEMORY_SCOPE_AGENT);
        dst[u] = squashf(sv);
        if (IT < 2) s[u] = 0.0f;          // reset for next iteration's atomics
    }
}

// ---------- A: blog[r,c] (+)= (1/B) sum_{b,o} u_hat[b,r,co]*v[b,co] ----------
// R8-identical compute; x column now staged coalesced from xT (gather moved
// to wtrans, done once instead of 2x1152 times).
template <bool FIRST>
__global__ __launch_bounds__(256, 2) void a_k(const float* __restrict__ xt,
                                              const float* __restrict__ wt,
                                              const float* __restrict__ v,
                                              float* __restrict__ blog,
                                              float* __restrict__ colbins) {
    const int r = blockIdx.x;
    const int t = threadIdx.x;
    const int w = t >> 6, lane = t & 63;
    const int co4 = lane, c = lane >> 2;

    __shared__ float4 xl[256];            // 128 b x 2 f4 = 4 KB
    __shared__ float  red[64];
    const float4* __restrict__ XT4 = (const float4*)xt;
    const float4* __restrict__ V4  = (const float4*)v;
    const float4* __restrict__ Wt4 = (const float4*)wt;

    xl[t] = XT4[r * 256 + t];             // coalesced (was 64-line gather)
    __syncthreads();

    float y[8][4];
    #pragma unroll
    for (int i = 0; i < 8; ++i)
        #pragma unroll
        for (int q = 0; q < 4; ++q) y[i][q] = 0.f;

    const int b0 = w * 32;
    #pragma unroll 4
    for (int bb = 0; bb < 32; ++bb) {
        const int b = b0 + bb;
        const float4 xa = xl[b * 2];
        const float4 xb = xl[b * 2 + 1];
        const float4 vv = V4[b * 64 + co4];
        y[0][0] = fmaf(xa.x, vv.x, y[0][0]); y[0][1] = fmaf(xa.x, vv.y, y[0][1]);
        y[0][2] = fmaf(xa.x, vv.z, y[0][2]); y[0][3] = fmaf(xa.x, vv.w, y[0][3]);
        y[1][0] = fmaf(xa.y, vv.x, y[1][0]); y[1][1] = fmaf(xa.y, vv.y, y[1][1]);
        y[1][2] = fmaf(xa.y, vv.z, y[1][2]); y[1][3] = fmaf(xa.y, vv.w, y[1][3]);
        y[2][0] = fmaf(xa.z, vv.x, y[2][0]); y[2][1] = fmaf(xa.z, vv.y, y[2][1]);
        y[2][2] = fmaf(xa.z, vv.z, y[2][2]); y[2][3] = fmaf(xa.z, vv.w, y[2][3]);
        y[3][0] = fmaf(xa.w, vv.x, y[3][0]); y[3][1] = fmaf(xa.w, vv.y, y[3][1]);
        y[3][2] = fmaf(xa.w, vv.z, y[3][2]); y[3][3] = fmaf(xa.w, vv.w, y[3][3]);
        y[4][0] = fmaf(xb.x, vv.x, y[4][0]); y[4][1] = fmaf(xb.x, vv.y, y[4][1]);
        y[4][2] = fmaf(xb.x, vv.z, y[4][2]); y[4][3] = fmaf(xb.x, vv.w, y[4][3]);
        y[5][0] = fmaf(xb.y, vv.x, y[5][0]); y[5][1] = fmaf(xb.y, vv.y, y[5][1]);
        y[5][2] = fmaf(xb.y, vv.z, y[5][2]); y[5][3] = fmaf(xb.y, vv.w, y[5][3]);
        y[6][0] = fmaf(xb.z, vv.x, y[6][0]); y[6][1] = fmaf(xb.z, vv.y, y[6][1]);
        y[6][2] = fmaf(xb.z, vv.z, y[6][2]); y[6][3] = fmaf(xb.z, vv.w, y[6][3]);
        y[7][0] = fmaf(xb.w, vv.x, y[7][0]); y[7][1] = fmaf(xb.w, vv.y, y[7][1]);
        y[7][2] = fmaf(xb.w, vv.z, y[7][2]); y[7][3] = fmaf(xb.w, vv.w, y[7][3]);
    }

    const float4* wp = Wt4 + ((size_t)r << 9) + co4;
    float part = 0.f;
    #pragma unroll
    for (int q = 0; q < 4; ++q) {
        const float4 w0 = wp[(2 * q) * 64];
        const float4 w1 = wp[(2 * q + 1) * 64];
        part += w0.x*y[0][q] + w0.y*y[1][q] + w0.z*y[2][q] + w0.w*y[3][q]
              + w1.x*y[4][q] + w1.y*y[5][q] + w1.z*y[6][q] + w1.w*y[7][q];
    }
    part += __shfl_xor(part, 1);
    part += __shfl_xor(part, 2);
    if ((lane & 3) == 0) red[w * 16 + c] = part;
    __syncthreads();
    if (t < 16) {
        const float val = ((red[t] + red[16 + t]) + (red[32 + t] + red[48 + t]))
                          * (1.0f / (float)B_);
        const int idx = r * 16 + t;
        const float nv = FIRST ? val : (blog[idx] + val);
        blog[idx] = nv;
        atomicAdd(&colbins[(r >> 4) * 16 + t], __expf(nv));  // 16-deep chains
    }
}

extern "C" void kernel_launch(void* const* d_in, const int* in_sizes, int n_in,
                              void* d_out, int out_size, void* d_ws, size_t ws_size,
                              hipStream_t stream) {
    const float* x = (const float*)d_in[0];   // [128,1152,8]
    const float* W = (const float*)d_in[1];   // [1,1152,16,16,8]
    float* out = (float*)d_out;               // [128,16,16]
    float* ws  = (float*)d_ws;                // ~14.5 MB used

    float* s    = ws + WS_S;
    float* v    = ws + WS_V;
    float* blog = ws + WS_BLOG;
    float* ctrl = ws + WS_CTRL;
    float* xt   = ws + WS_XT;
    float* wt   = ws + WS_WT;

    unsigned int* ctr = (unsigned int*)ctrl;  // ctr0/1/2 at +0/+16/+32
    float* cs0 = ctrl + 64;                   // 72x16 bins
    float* cs1 = ctrl + 1216;                 // 72x16 bins

    // transposes + replay-safe zeroing of s/counters/bins
    wtrans_k<<<R_, 512, 0, stream>>>(W, x, wt, xt, s, ctrl);

    // iter 0 (softmax(0) == 1/R): gemm accumulates s atomically, tail squashes -> v
    gemm_s_k<0><<<dim3(16, RS_), 256, 0, stream>>>(x, wt, nullptr, nullptr, s, v, ctr + 0);
    a_k<true ><<<R_, 256, 0, stream>>>(xt, wt, v, blog, cs0);

    // iter 1
    gemm_s_k<1><<<dim3(16, RS_), 256, 0, stream>>>(x, wt, blog, cs0, s, v, ctr + 16);
    a_k<false><<<R_, 256, 0, stream>>>(xt, wt, v, blog, cs1);

    // iter 2 — tail writes squash(s) directly to out
    gemm_s_k<2><<<dim3(16, RS_), 256, 0, stream>>>(x, wt, blog, cs1, s, out, ctr + 32);
}

// Round 10
// 229.088 us; speedup vs baseline: 1.7279x; 1.7279x over previous
//
#include <hip/hip_runtime.h>
#include <math.h>

#define B_   128
#define R_   1152
#define RS_  64
#define RCH_ 18            // R_/RS_
#define NBINS 72           // 1152/16 colsum bins

// ws float offsets
#define WS_SP   0          // RS_*32768 = 2097152
#define WS_V    2097152    // 32768
#define WS_BLOG 2129920    // 18432
#define WS_CTRL 2148352    // 2432 floats: cs0 @+0 (72*16), cs1 @+1280
#define WS_XT   2150784    // 1179648 (xT4[r*256 + b*2 + h])
#define WS_WT   3330432    // 2359296 (Wt4[r*512 + d*64 + co4])

__device__ __forceinline__ float squashf(float s) {
    return s * fabsf(s) / (1.0f + s * s);
}

// ---------- G: sp[rs][b][co] = sum_{r in chunk,i} x[b,r,i]*cw[r,c]*W[r,co,i]
// grid dim3(16 bt, 64 rs) x 256 — R8's proven body and hot loop.
// IT==0 additionally absorbs wtrans: all blocks read RAW W (per-lane 8
// contiguous float4 -> wave covers the full 8KB row, coalesced); bt==0
// blocks store Wt, bt==1 blocks build xT, (bt==2,rs==0) zeroes ctrl.
// Stream order makes Wt/xT/ctrl visible to later dispatches (kernel-boundary
// coherence) — no fences, no atomics, no spins (R7/R9 lessons).
// IT>=1: cw = exp(blog)*1/colsum from 72x16 bins; reads Wt coalesced.
template <int IT>
__global__ __launch_bounds__(256) void gemm_s_k(const float* __restrict__ x,
                                                const float* __restrict__ W,
                                                float* __restrict__ wt,
                                                float* __restrict__ xt,
                                                const float* __restrict__ blog,
                                                const float* __restrict__ colbins,
                                                float* __restrict__ sp,
                                                float* __restrict__ ctrl) {
    const int bt  = blockIdx.x;           // 0..15 (8 b each)
    const int rs  = blockIdx.y;
    const int t   = threadIdx.x;
    const int co4 = t & 63;
    const int b4  = t >> 6;               // 0..3 (2 b each)
    const int c   = co4 >> 2;
    const int r0  = rs * RCH_;

    __shared__ float4 xl4[288];           // 8 b x 18 r x 2 f4 = 4.6 KB
    __shared__ float  cwl[RCH_ * 16];
    __shared__ float  colinv_sh[16];
    __shared__ float  psum[256];

    const float4* __restrict__ X4  = (const float4*)x;
    const float4* __restrict__ W4  = (const float4*)W;
    float4* __restrict__ Wt4 = (float4*)wt;
    float4* __restrict__ XT4 = (float4*)xt;

    // stage x tile: 8 b x 18 r x 2 f4
    #pragma unroll
    for (int k = 0; k < 2; ++k) {
        const int u = t + k * 256;
        if (u < 288) {
            const int bl = u / 36, rem = u % 36;
            xl4[u] = X4[((bt * 8 + bl) * R_ + r0) * 2 + rem];
        }
    }

    if (IT == 0) {
        // absorbed wtrans side duties (no sync needed; consumed by later dispatches)
        if (bt == 1) {
            for (int rr = 0; rr < RCH_; ++rr) {
                const int r = r0 + rr;
                XT4[r * 256 + t] = X4[((t >> 1) * R_ + r) * 2 + (t & 1)];
            }
        }
        if (bt == 2 && rs == 0) {
            for (int u = t; u < 2432; u += 256) ctrl[u] = 0.0f;
        }
    } else {
        // prepass: colinv from bins (16 j-lanes x 16 cc), then cwl rows
        const int cc = t & 15, jb = t >> 4;
        float sm = 0.f;
        for (int j = jb; j < NBINS; j += 16) sm += colbins[j * 16 + cc];
        psum[t] = sm;
        __syncthreads();
        if (t < 16) {
            float tot = 0.f;
            #pragma unroll
            for (int k2 = 0; k2 < 16; ++k2) tot += psum[k2 * 16 + t];
            colinv_sh[t] = 1.0f / tot;
        }
        __syncthreads();
        for (int u2 = t; u2 < RCH_ * 16; u2 += 256) {
            const int rl = u2 >> 4, c2 = u2 & 15;
            cwl[u2] = __expf(blog[(r0 + rl) * 16 + c2]) * colinv_sh[c2];
        }
    }
    __syncthreads();

    float acc[2][4];
    #pragma unroll
    for (int j = 0; j < 2; ++j)
        #pragma unroll
        for (int q = 0; q < 4; ++q) acc[j][q] = 0.f;

    // R8-identical hot loop (named w0..w7, unroll 3, j-extent 2)
    #pragma unroll 3
    for (int rr = 0; rr < RCH_; ++rr) {
        const float cwv = (IT == 0) ? (1.0f / (float)R_) : cwl[rr * 16 + c];
        float4 w0, w1, w2, w3, w4, w5, w6, w7;
        if (IT == 0) {
            // raw layout: lane's 8 fragments are 128 B contiguous
            const float4* wp = W4 + ((size_t)(r0 + rr) << 9) + co4 * 8;
            w0 = wp[0]; w1 = wp[1]; w2 = wp[2]; w3 = wp[3];
            w4 = wp[4]; w5 = wp[5]; w6 = wp[6]; w7 = wp[7];
            if (bt == 0) {                 // emit Wt for later kernels
                float4* wo = Wt4 + ((size_t)(r0 + rr) << 9) + co4;
                wo[  0] = w0; wo[ 64] = w1; wo[128] = w2; wo[192] = w3;
                wo[256] = w4; wo[320] = w5; wo[384] = w6; wo[448] = w7;
            }
        } else {
            const float4* wp = Wt4 + ((size_t)(r0 + rr) << 9) + co4;  // 16B lane-stride
            w0 = wp[  0]; w1 = wp[ 64]; w2 = wp[128]; w3 = wp[192];
            w4 = wp[256]; w5 = wp[320]; w6 = wp[384]; w7 = wp[448];
        }
        #pragma unroll
        for (int j = 0; j < 2; ++j) {
            const float4 xa = xl4[(b4 * 2 + j) * 36 + rr * 2];
            const float4 xb = xl4[(b4 * 2 + j) * 36 + rr * 2 + 1];
            const float d0 = w0.x*xa.x + w0.y*xa.y + w0.z*xa.z + w0.w*xa.w
                           + w1.x*xb.x + w1.y*xb.y + w1.z*xb.z + w1.w*xb.w;
            const float d1 = w2.x*xa.x + w2.y*xa.y + w2.z*xa.z + w2.w*xa.w
                           + w3.x*xb.x + w3.y*xb.y + w3.z*xb.z + w3.w*xb.w;
            const float d2 = w4.x*xa.x + w4.y*xa.y + w4.z*xa.z + w4.w*xa.w
                           + w5.x*xb.x + w5.y*xb.y + w5.z*xb.z + w5.w*xb.w;
            const float d3 = w6.x*xa.x + w6.y*xa.y + w6.z*xa.z + w6.w*xa.w
                           + w7.x*xb.x + w7.y*xb.y + w7.z*xb.z + w7.w*xb.w;
            acc[j][0] = fmaf(cwv, d0, acc[j][0]);
            acc[j][1] = fmaf(cwv, d1, acc[j][1]);
            acc[j][2] = fmaf(cwv, d2, acc[j][2]);
            acc[j][3] = fmaf(cwv, d3, acc[j][3]);
        }
    }

    float4* sp4 = (float4*)sp;
    #pragma unroll
    for (int j = 0; j < 2; ++j) {
        const int b = bt * 8 + b4 * 2 + j;
        float4 o4; o4.x = acc[j][0]; o4.y = acc[j][1]; o4.z = acc[j][2]; o4.w = acc[j][3];
        sp4[(rs * B_ + b) * 64 + co4] = o4;
    }
}

// ---------- R: v[b,co] = squash(sum_k sp[k][b][co]); grid 256 x 512 (R8-identical)
__global__ __launch_bounds__(512) void reduce_squash_k(const float* __restrict__ sp,
                                                       float* __restrict__ outv) {
    const int t   = threadIdx.x;
    const int li  = t & 127;
    const int kq  = t >> 7;               // 0..3 (16 slices each)
    const int idx = blockIdx.x * 128 + li;
    const float* p = sp + (size_t)kq * 16 * 32768 + idx;
    float a0 = 0.f, a1 = 0.f, a2 = 0.f, a3 = 0.f;
    #pragma unroll
    for (int k = 0; k < 16; k += 4) {
        a0 += p[(k + 0) * 32768];
        a1 += p[(k + 1) * 32768];
        a2 += p[(k + 2) * 32768];
        a3 += p[(k + 3) * 32768];
    }
    __shared__ float red[512];
    red[t] = (a0 + a1) + (a2 + a3);
    __syncthreads();
    if (t < 128) {
        const float s = (red[t] + red[t + 128]) + (red[t + 256] + red[t + 384]);
        outv[idx] = squashf(s);
    }
}

#define ACC32(Y, XA, XB) \
    Y[0][0]=fmaf(XA.x,vv.x,Y[0][0]); Y[0][1]=fmaf(XA.x,vv.y,Y[0][1]); \
    Y[0][2]=fmaf(XA.x,vv.z,Y[0][2]); Y[0][3]=fmaf(XA.x,vv.w,Y[0][3]); \
    Y[1][0]=fmaf(XA.y,vv.x,Y[1][0]); Y[1][1]=fmaf(XA.y,vv.y,Y[1][1]); \
    Y[1][2]=fmaf(XA.y,vv.z,Y[1][2]); Y[1][3]=fmaf(XA.y,vv.w,Y[1][3]); \
    Y[2][0]=fmaf(XA.z,vv.x,Y[2][0]); Y[2][1]=fmaf(XA.z,vv.y,Y[2][1]); \
    Y[2][2]=fmaf(XA.z,vv.z,Y[2][2]); Y[2][3]=fmaf(XA.z,vv.w,Y[2][3]); \
    Y[3][0]=fmaf(XA.w,vv.x,Y[3][0]); Y[3][1]=fmaf(XA.w,vv.y,Y[3][1]); \
    Y[3][2]=fmaf(XA.w,vv.z,Y[3][2]); Y[3][3]=fmaf(XA.w,vv.w,Y[3][3]); \
    Y[4][0]=fmaf(XB.x,vv.x,Y[4][0]); Y[4][1]=fmaf(XB.x,vv.y,Y[4][1]); \
    Y[4][2]=fmaf(XB.x,vv.z,Y[4][2]); Y[4][3]=fmaf(XB.x,vv.w,Y[4][3]); \
    Y[5][0]=fmaf(XB.y,vv.x,Y[5][0]); Y[5][1]=fmaf(XB.y,vv.y,Y[5][1]); \
    Y[5][2]=fmaf(XB.y,vv.z,Y[5][2]); Y[5][3]=fmaf(XB.y,vv.w,Y[5][3]); \
    Y[6][0]=fmaf(XB.z,vv.x,Y[6][0]); Y[6][1]=fmaf(XB.z,vv.y,Y[6][1]); \
    Y[6][2]=fmaf(XB.z,vv.z,Y[6][2]); Y[6][3]=fmaf(XB.z,vv.w,Y[6][3]); \
    Y[7][0]=fmaf(XB.w,vv.x,Y[7][0]); Y[7][1]=fmaf(XB.w,vv.y,Y[7][1]); \
    Y[7][2]=fmaf(XB.w,vv.z,Y[7][2]); Y[7][3]=fmaf(XB.w,vv.w,Y[7][3]);

// ---------- A: blog[r,c] (+)= (1/B) sum_{b,o} u_hat[b,r,co]*v[b,co] ----------
// 2 r per block (576 blocks): each vv load feeds 64 FMAs across two
// independent accumulator sets (2x ILP vs R8), v traffic halved.
// launch_bounds(256,2): VGPR cap 128, live state ~95 -> registers.
template <bool FIRST>
__global__ __launch_bounds__(256, 2) void a_k(const float* __restrict__ xt,
                                              const float* __restrict__ wt,
                                              const float* __restrict__ v,
                                              float* __restrict__ blog,
                                              float* __restrict__ colbins) {
    const int r0 = blockIdx.x * 2;
    const int t  = threadIdx.x;
    const int w  = t >> 6, lane = t & 63;
    const int co4 = lane, c = lane >> 2;

    __shared__ float4 xl[512];            // [b][rr][h]: 128 b x 2 r x 2 f4 = 8 KB
    __shared__ float  red[128];
    const float4* __restrict__ XT4 = (const float4*)xt;
    const float4* __restrict__ V4  = (const float4*)v;
    const float4* __restrict__ Wt4 = (const float4*)wt;

    #pragma unroll
    for (int k = 0; k < 2; ++k) {
        const int u = t + k * 256;        // b=u>>2, rr=(u&3)>>1, h=u&1
        xl[u] = XT4[(r0 + ((u & 3) >> 1)) * 256 + (u >> 2) * 2 + (u & 1)];
    }
    __syncthreads();

    float y0[8][4], y1[8][4];
    #pragma unroll
    for (int i = 0; i < 8; ++i)
        #pragma unroll
        for (int q = 0; q < 4; ++q) { y0[i][q] = 0.f; y1[i][q] = 0.f; }

    const int b0 = w * 32;
    #pragma unroll 2
    for (int bb = 0; bb < 32; ++bb) {
        const int b = b0 + bb;
        const float4 xa0 = xl[b * 4 + 0];
        const float4 xb0 = xl[b * 4 + 1];
        const float4 xa1 = xl[b * 4 + 2];
        const float4 xb1 = xl[b * 4 + 3];
        const float4 vv  = V4[b * 64 + co4];
        ACC32(y0, xa0, xb0)
        ACC32(y1, xa1, xb1)
    }

    float part0 = 0.f, part1 = 0.f;
    {
        const float4* wp0 = Wt4 + ((size_t)r0 << 9) + co4;
        const float4* wp1 = Wt4 + ((size_t)(r0 + 1) << 9) + co4;
        #pragma unroll
        for (int q = 0; q < 4; ++q) {
            const float4 a0 = wp0[(2 * q) * 64], a1 = wp0[(2 * q + 1) * 64];
            part0 += a0.x*y0[0][q] + a0.y*y0[1][q] + a0.z*y0[2][q] + a0.w*y0[3][q]
                   + a1.x*y0[4][q] + a1.y*y0[5][q] + a1.z*y0[6][q] + a1.w*y0[7][q];
            const float4 b0v = wp1[(2 * q) * 64], b1v = wp1[(2 * q + 1) * 64];
            part1 += b0v.x*y1[0][q] + b0v.y*y1[1][q] + b0v.z*y1[2][q] + b0v.w*y1[3][q]
                   + b1v.x*y1[4][q] + b1v.y*y1[5][q] + b1v.z*y1[6][q] + b1v.w*y1[7][q];
        }
    }
    part0 += __shfl_xor(part0, 1); part0 += __shfl_xor(part0, 2);
    part1 += __shfl_xor(part1, 1); part1 += __shfl_xor(part1, 2);
    if ((lane & 3) == 0) {
        red[w * 16 + c]      = part0;
        red[64 + w * 16 + c] = part1;
    }
    __syncthreads();
    if (t < 32) {
        const int rr2 = t >> 4, cc = t & 15;
        const float* rb = red + rr2 * 64;
        const float val = ((rb[cc] + rb[16 + cc]) + (rb[32 + cc] + rb[48 + cc]))
                          * (1.0f / (float)B_);
        const int r = r0 + rr2;
        const int idx = r * 16 + cc;
        const float nv = FIRST ? val : (blog[idx] + val);
        blog[idx] = nv;
        atomicAdd(&colbins[(r >> 4) * 16 + cc], __expf(nv));  // 16-deep chains
    }
}

extern "C" void kernel_launch(void* const* d_in, const int* in_sizes, int n_in,
                              void* d_out, int out_size, void* d_ws, size_t ws_size,
                              hipStream_t stream) {
    const float* x = (const float*)d_in[0];   // [128,1152,8]
    const float* W = (const float*)d_in[1];   // [1,1152,16,16,8]
    float* out = (float*)d_out;               // [128,16,16]
    float* ws  = (float*)d_ws;                // ~22.8 MB used

    float* sp   = ws + WS_SP;
    float* v    = ws + WS_V;
    float* blog = ws + WS_BLOG;
    float* ctrl = ws + WS_CTRL;
    float* xt   = ws + WS_XT;
    float* wt   = ws + WS_WT;

    float* cs0 = ctrl;                        // 72x16 bins
    float* cs1 = ctrl + 1280;                 // 72x16 bins

    // iter 0 (softmax(0) == 1/R): gemm0 absorbs wtrans (Wt, xT, ctrl-zero)
    gemm_s_k<0><<<dim3(16, RS_), 256, 0, stream>>>(x, W, wt, xt, nullptr, nullptr, sp, ctrl);
    reduce_squash_k<<<256, 512, 0, stream>>>(sp, v);
    a_k<true ><<<576, 256, 0, stream>>>(xt, wt, v, blog, cs0);

    // iter 1
    gemm_s_k<1><<<dim3(16, RS_), 256, 0, stream>>>(x, W, wt, xt, blog, cs0, sp, ctrl);
    reduce_squash_k<<<256, 512, 0, stream>>>(sp, v);
    a_k<false><<<576, 256, 0, stream>>>(xt, wt, v, blog, cs1);

    // iter 2
    gemm_s_k<2><<<dim3(16, RS_), 256, 0, stream>>>(x, W, wt, xt, blog, cs1, sp, ctrl);
    reduce_squash_k<<<256, 512, 0, stream>>>(sp, out);
}

// Round 11
// 169.465 us; speedup vs baseline: 2.3359x; 1.3518x over previous
//
#include <hip/hip_runtime.h>
#include <math.h>

#define B_   128
#define R_   1152
#define RS_  64
#define RCH_ 18            // R_/RS_
#define NBINS 72           // 1152/16 colsum bins

// ws float offsets
#define WS_SP   0          // RS_*32768 = 2097152
#define WS_V    2097152    // 32768
#define WS_BLOG 2129920    // 18432
#define WS_CTRL 2148352    // 2432 floats: cs0 @+0 (72*16), cs1 @+1280
#define WS_XT   2150784    // 1179648 (xT4[r*256 + b*2 + h])
#define WS_WT   3330432    // 2359296 (Wt4[r*512 + d*64 + co4])

__device__ __forceinline__ float squashf(float s) {
    return s * fabsf(s) / (1.0f + s * s);
}

// ---------- T: Wt transpose (pitch-65 LDS swizzle) + xT gather + ctrl zero.
// All three duties proven in R9's passing run. Raw-W is read HERE with the
// coalesced t=co4*8+d mapping (one 16B load/lane, full-sector use) — R10
// showed reading raw W per-lane-contiguous in gemm costs 8x sector over-fetch.
__global__ __launch_bounds__(512) void wtrans_k(const float* __restrict__ W,
                                                const float* __restrict__ x,
                                                float* __restrict__ wt,
                                                float* __restrict__ xt,
                                                float* __restrict__ ctrl) {
    const int r = blockIdx.x;
    const int t = threadIdx.x;
    __shared__ float4 sh[520];
    const float4* __restrict__ W4 = (const float4*)W;
    const float4* __restrict__ X4 = (const float4*)x;
    float4* __restrict__ Wt4 = (float4*)wt;
    float4* __restrict__ XT4 = (float4*)xt;

    if (r == 0) {
        for (int u = t; u < 2432; u += 512) ctrl[u] = 0.0f;
    }
    // x column gather done ONCE here (a_k then loads it coalesced)
    if (t < 256) {
        XT4[r * 256 + t] = X4[((t >> 1) * R_ + r) * 2 + (t & 1)];
    }

    sh[(t & 7) * 65 + (t >> 3)] = W4[r * 512 + t];     // t = co4*8 + d
    __syncthreads();
    Wt4[r * 512 + t] = sh[(t >> 6) * 65 + (t & 63)];   // t = d*64 + co4
}

// ---------- G: sp[rs][b][co] = sum_{r in chunk,i} x[b,r,i]*cw[r,c]*W[r,co,i]
// grid dim3(16 bt, 64 rs) x 256 — R8's proven body and hot loop, unchanged.
// FIRST: cw = 1/R exactly. Else cw = exp(blog)*1/colsum from 72x16 bins.
template <bool FIRST>
__global__ __launch_bounds__(256) void gemm_s_k(const float* __restrict__ x,
                                                const float* __restrict__ wt,
                                                const float* __restrict__ blog,
                                                const float* __restrict__ colbins,
                                                float* __restrict__ sp) {
    const int bt  = blockIdx.x;           // 0..15 (8 b each)
    const int rs  = blockIdx.y;
    const int t   = threadIdx.x;
    const int co4 = t & 63;
    const int b4  = t >> 6;               // 0..3 (2 b each)
    const int c   = co4 >> 2;
    const int r0  = rs * RCH_;

    __shared__ float4 xl4[288];           // 8 b x 18 r x 2 f4 = 4.6 KB
    __shared__ float  cwl[RCH_ * 16];
    __shared__ float  colinv_sh[16];
    __shared__ float  psum[256];

    const float4* __restrict__ X4  = (const float4*)x;
    const float4* __restrict__ Wt4 = (const float4*)wt;

    // stage x tile: 8 b x 18 r x 2 f4
    #pragma unroll
    for (int k = 0; k < 2; ++k) {
        const int u = t + k * 256;
        if (u < 288) {
            const int bl = u / 36, rem = u % 36;
            xl4[u] = X4[((bt * 8 + bl) * R_ + r0) * 2 + rem];
        }
    }

    // prepass: colinv from bins (16 j-lanes x 16 cc), then cwl rows
    if (!FIRST) {
        const int cc = t & 15, jb = t >> 4;
        float sm = 0.f;
        for (int j = jb; j < NBINS; j += 16) sm += colbins[j * 16 + cc];
        psum[t] = sm;
        __syncthreads();
        if (t < 16) {
            float tot = 0.f;
            #pragma unroll
            for (int k2 = 0; k2 < 16; ++k2) tot += psum[k2 * 16 + t];
            colinv_sh[t] = 1.0f / tot;
        }
        __syncthreads();
        for (int u2 = t; u2 < RCH_ * 16; u2 += 256) {
            const int rl = u2 >> 4, c2 = u2 & 15;
            cwl[u2] = __expf(blog[(r0 + rl) * 16 + c2]) * colinv_sh[c2];
        }
    }
    __syncthreads();

    float acc[2][4];
    #pragma unroll
    for (int j = 0; j < 2; ++j)
        #pragma unroll
        for (int q = 0; q < 4; ++q) acc[j][q] = 0.f;

    // R8-identical hot loop (named const w0..w7, unroll 3, j-extent 2)
    #pragma unroll 3
    for (int rr = 0; rr < RCH_; ++rr) {
        const float cwv = FIRST ? (1.0f / (float)R_) : cwl[rr * 16 + c];
        const float4* wp = Wt4 + ((size_t)(r0 + rr) << 9) + co4;   // lane-stride 16B
        const float4 w0 = wp[  0], w1 = wp[ 64], w2 = wp[128], w3 = wp[192];
        const float4 w4 = wp[256], w5 = wp[320], w6 = wp[384], w7 = wp[448];
        #pragma unroll
        for (int j = 0; j < 2; ++j) {
            const float4 xa = xl4[(b4 * 2 + j) * 36 + rr * 2];
            const float4 xb = xl4[(b4 * 2 + j) * 36 + rr * 2 + 1];
            const float d0 = w0.x*xa.x + w0.y*xa.y + w0.z*xa.z + w0.w*xa.w
                           + w1.x*xb.x + w1.y*xb.y + w1.z*xb.z + w1.w*xb.w;
            const float d1 = w2.x*xa.x + w2.y*xa.y + w2.z*xa.z + w2.w*xa.w
                           + w3.x*xb.x + w3.y*xb.y + w3.z*xb.z + w3.w*xb.w;
            const float d2 = w4.x*xa.x + w4.y*xa.y + w4.z*xa.z + w4.w*xa.w
                           + w5.x*xb.x + w5.y*xb.y + w5.z*xb.z + w5.w*xb.w;
            const float d3 = w6.x*xa.x + w6.y*xa.y + w6.z*xa.z + w6.w*xa.w
                           + w7.x*xb.x + w7.y*xb.y + w7.z*xb.z + w7.w*xb.w;
            acc[j][0] = fmaf(cwv, d0, acc[j][0]);
            acc[j][1] = fmaf(cwv, d1, acc[j][1]);
            acc[j][2] = fmaf(cwv, d2, acc[j][2]);
            acc[j][3] = fmaf(cwv, d3, acc[j][3]);
        }
    }

    float4* sp4 = (float4*)sp;
    #pragma unroll
    for (int j = 0; j < 2; ++j) {
        const int b = bt * 8 + b4 * 2 + j;
        float4 o4; o4.x = acc[j][0]; o4.y = acc[j][1]; o4.z = acc[j][2]; o4.w = acc[j][3];
        sp4[(rs * B_ + b) * 64 + co4] = o4;
    }
}

// ---------- R: v[b,co] = squash(sum_k sp[k][b][co]); grid 256 x 512 (R8-identical)
__global__ __launch_bounds__(512) void reduce_squash_k(const float* __restrict__ sp,
                                                       float* __restrict__ outv) {
    const int t   = threadIdx.x;
    const int li  = t & 127;
    const int kq  = t >> 7;               // 0..3 (16 slices each)
    const int idx = blockIdx.x * 128 + li;
    const float* p = sp + (size_t)kq * 16 * 32768 + idx;
    float a0 = 0.f, a1 = 0.f, a2 = 0.f, a3 = 0.f;
    #pragma unroll
    for (int k = 0; k < 16; k += 4) {
        a0 += p[(k + 0) * 32768];
        a1 += p[(k + 1) * 32768];
        a2 += p[(k + 2) * 32768];
        a3 += p[(k + 3) * 32768];
    }
    __shared__ float red[512];
    red[t] = (a0 + a1) + (a2 + a3);
    __syncthreads();
    if (t < 128) {
        const float s = (red[t] + red[t + 128]) + (red[t + 256] + red[t + 384]);
        outv[idx] = squashf(s);
    }
}

#define ACC32(Y, XA, XB) \
    Y[0][0]=fmaf(XA.x,vv.x,Y[0][0]); Y[0][1]=fmaf(XA.x,vv.y,Y[0][1]); \
    Y[0][2]=fmaf(XA.x,vv.z,Y[0][2]); Y[0][3]=fmaf(XA.x,vv.w,Y[0][3]); \
    Y[1][0]=fmaf(XA.y,vv.x,Y[1][0]); Y[1][1]=fmaf(XA.y,vv.y,Y[1][1]); \
    Y[1][2]=fmaf(XA.y,vv.z,Y[1][2]); Y[1][3]=fmaf(XA.y,vv.w,Y[1][3]); \
    Y[2][0]=fmaf(XA.z,vv.x,Y[2][0]); Y[2][1]=fmaf(XA.z,vv.y,Y[2][1]); \
    Y[2][2]=fmaf(XA.z,vv.z,Y[2][2]); Y[2][3]=fmaf(XA.z,vv.w,Y[2][3]); \
    Y[3][0]=fmaf(XA.w,vv.x,Y[3][0]); Y[3][1]=fmaf(XA.w,vv.y,Y[3][1]); \
    Y[3][2]=fmaf(XA.w,vv.z,Y[3][2]); Y[3][3]=fmaf(XA.w,vv.w,Y[3][3]); \
    Y[4][0]=fmaf(XB.x,vv.x,Y[4][0]); Y[4][1]=fmaf(XB.x,vv.y,Y[4][1]); \
    Y[4][2]=fmaf(XB.x,vv.z,Y[4][2]); Y[4][3]=fmaf(XB.x,vv.w,Y[4][3]); \
    Y[5][0]=fmaf(XB.y,vv.x,Y[5][0]); Y[5][1]=fmaf(XB.y,vv.y,Y[5][1]); \
    Y[5][2]=fmaf(XB.y,vv.z,Y[5][2]); Y[5][3]=fmaf(XB.y,vv.w,Y[5][3]); \
    Y[6][0]=fmaf(XB.z,vv.x,Y[6][0]); Y[6][1]=fmaf(XB.z,vv.y,Y[6][1]); \
    Y[6][2]=fmaf(XB.z,vv.z,Y[6][2]); Y[6][3]=fmaf(XB.z,vv.w,Y[6][3]); \
    Y[7][0]=fmaf(XB.w,vv.x,Y[7][0]); Y[7][1]=fmaf(XB.w,vv.y,Y[7][1]); \
    Y[7][2]=fmaf(XB.w,vv.z,Y[7][2]); Y[7][3]=fmaf(XB.w,vv.w,Y[7][3]);

// ---------- A: blog[r,c] (+)= (1/B) sum_{b,o} u_hat[b,r,co]*v[b,co] ----------
// R10's proven version: 2 r per block (576 blocks), each vv load feeds 64
// FMAs across two independent accumulator sets; x staged coalesced from xT.
template <bool FIRST>
__global__ __launch_bounds__(256, 2) void a_k(const float* __restrict__ xt,
                                              const float* __restrict__ wt,
                                              const float* __restrict__ v,
                                              float* __restrict__ blog,
                                              float* __restrict__ colbins) {
    const int r0 = blockIdx.x * 2;
    const int t  = threadIdx.x;
    const int w  = t >> 6, lane = t & 63;
    const int co4 = lane, c = lane >> 2;

    __shared__ float4 xl[512];            // [b][rr][h]: 128 b x 2 r x 2 f4 = 8 KB
    __shared__ float  red[128];
    const float4* __restrict__ XT4 = (const float4*)xt;
    const float4* __restrict__ V4  = (const float4*)v;
    const float4* __restrict__ Wt4 = (const float4*)wt;

    #pragma unroll
    for (int k = 0; k < 2; ++k) {
        const int u = t + k * 256;        // b=u>>2, rr=(u&3)>>1, h=u&1
        xl[u] = XT4[(r0 + ((u & 3) >> 1)) * 256 + (u >> 2) * 2 + (u & 1)];
    }
    __syncthreads();

    float y0[8][4], y1[8][4];
    #pragma unroll
    for (int i = 0; i < 8; ++i)
        #pragma unroll
        for (int q = 0; q < 4; ++q) { y0[i][q] = 0.f; y1[i][q] = 0.f; }

    const int b0 = w * 32;
    #pragma unroll 2
    for (int bb = 0; bb < 32; ++bb) {
        const int b = b0 + bb;
        const float4 xa0 = xl[b * 4 + 0];
        const float4 xb0 = xl[b * 4 + 1];
        const float4 xa1 = xl[b * 4 + 2];
        const float4 xb1 = xl[b * 4 + 3];
        const float4 vv  = V4[b * 64 + co4];
        ACC32(y0, xa0, xb0)
        ACC32(y1, xa1, xb1)
    }

    float part0 = 0.f, part1 = 0.f;
    {
        const float4* wp0 = Wt4 + ((size_t)r0 << 9) + co4;
        const float4* wp1 = Wt4 + ((size_t)(r0 + 1) << 9) + co4;
        #pragma unroll
        for (int q = 0; q < 4; ++q) {
            const float4 a0 = wp0[(2 * q) * 64], a1 = wp0[(2 * q + 1) * 64];
            part0 += a0.x*y0[0][q] + a0.y*y0[1][q] + a0.z*y0[2][q] + a0.w*y0[3][q]
                   + a1.x*y0[4][q] + a1.y*y0[5][q] + a1.z*y0[6][q] + a1.w*y0[7][q];
            const float4 b0v = wp1[(2 * q) * 64], b1v = wp1[(2 * q + 1) * 64];
            part1 += b0v.x*y1[0][q] + b0v.y*y1[1][q] + b0v.z*y1[2][q] + b0v.w*y1[3][q]
                   + b1v.x*y1[4][q] + b1v.y*y1[5][q] + b1v.z*y1[6][q] + b1v.w*y1[7][q];
        }
    }
    part0 += __shfl_xor(part0, 1); part0 += __shfl_xor(part0, 2);
    part1 += __shfl_xor(part1, 1); part1 += __shfl_xor(part1, 2);
    if ((lane & 3) == 0) {
        red[w * 16 + c]      = part0;
        red[64 + w * 16 + c] = part1;
    }
    __syncthreads();
    if (t < 32) {
        const int rr2 = t >> 4, cc = t & 15;
        const float* rb = red + rr2 * 64;
        const float val = ((rb[cc] + rb[16 + cc]) + (rb[32 + cc] + rb[48 + cc]))
                          * (1.0f / (float)B_);
        const int r = r0 + rr2;
        const int idx = r * 16 + cc;
        const float nv = FIRST ? val : (blog[idx] + val);
        blog[idx] = nv;
        atomicAdd(&colbins[(r >> 4) * 16 + cc], __expf(nv));  // 16-deep chains
    }
}

extern "C" void kernel_launch(void* const* d_in, const int* in_sizes, int n_in,
                              void* d_out, int out_size, void* d_ws, size_t ws_size,
                              hipStream_t stream) {
    const float* x = (const float*)d_in[0];   // [128,1152,8]
    const float* W = (const float*)d_in[1];   // [1,1152,16,16,8]
    float* out = (float*)d_out;               // [128,16,16]
    float* ws  = (float*)d_ws;                // ~22.8 MB used

    float* sp   = ws + WS_SP;
    float* v    = ws + WS_V;
    float* blog = ws + WS_BLOG;
    float* ctrl = ws + WS_CTRL;
    float* xt   = ws + WS_XT;
    float* wt   = ws + WS_WT;

    float* cs0 = ctrl;                        // 72x16 bins
    float* cs1 = ctrl + 1280;                 // 72x16 bins

    // transposes (Wt via coalesced LDS swizzle, xT gather) + ctrl zero
    wtrans_k<<<R_, 512, 0, stream>>>(W, x, wt, xt, ctrl);

    // iter 0 (softmax(0) == 1/R exactly)
    gemm_s_k<true ><<<dim3(16, RS_), 256, 0, stream>>>(x, wt, nullptr, nullptr, sp);
    reduce_squash_k<<<256, 512, 0, stream>>>(sp, v);
    a_k<true ><<<576, 256, 0, stream>>>(xt, wt, v, blog, cs0);

    // iter 1
    gemm_s_k<false><<<dim3(16, RS_), 256, 0, stream>>>(x, wt, blog, cs0, sp);
    reduce_squash_k<<<256, 512, 0, stream>>>(sp, v);
    a_k<false><<<576, 256, 0, stream>>>(xt, wt, v, blog, cs1);

    // iter 2
    gemm_s_k<false><<<dim3(16, RS_), 256, 0, stream>>>(x, wt, blog, cs1, sp);
    reduce_squash_k<<<256, 512, 0, stream>>>(sp, out);
}